// Round 12
// baseline (474.167 us; speedup 1.0000x reference)
//
#include <hip/hip_runtime.h>
#include <hip/hip_bf16.h>

#define T_LEN 512
#define HID 50
#define NBATCH 4096

using short8  = __attribute__((ext_vector_type(8))) short;
using floatx4 = __attribute__((ext_vector_type(4))) float;

__device__ __forceinline__ float sigm(float v) {
  return __builtin_amdgcn_rcpf(1.0f + __builtin_amdgcn_exp2f(-1.442695041f * v));
}
__device__ __forceinline__ float tanh_f(float v) {
  return 1.0f - 2.0f * __builtin_amdgcn_rcpf(1.0f + __builtin_amdgcn_exp2f(2.885390082f * v));
}
__device__ __forceinline__ unsigned short bf16hi(float v) {
  __hip_bfloat16 b = __float2bfloat16(v);
  return *(unsigned short*)&b;
}
__device__ __forceinline__ float bf16tof(unsigned short u) {
  return __uint_as_float((unsigned int)u << 16);
}

// h plane: 16 rows (m=batch) x 64 bf16 cols, row = 128 B, XOR swizzle ((m&7)<<4).
// Cols: 0..49 h_hi ; 50..52 x_hi ; 53 = 1.0 ; 54..56 x_lo ; 57..63 = 0.
// k-bijection (A reads and B build): k = 32*f + 8*kg + e.
// 2-wave block: wave w owns units 32w..32w+31 (two 16-wide N-tiles).
__global__ __launch_bounds__(128, 1)
void gru_mfma_kernel(const float* __restrict__ x,
                     const float* __restrict__ W_ih,
                     const float* __restrict__ W_hh,
                     const float* __restrict__ b_ih,
                     const float* __restrict__ b_hh,
                     const float* __restrict__ W_fc,
                     const float* __restrict__ b_fc,
                     float* __restrict__ out) {
  // LDS: [0,12288) x-chunk [i64][c3][m16] f32 ; [12288,16384) 2 h planes
  __shared__ alignas(16) unsigned char lds[16384];
  char* xs   = (char*)lds;
  char* hbuf = (char*)lds + 12288;

  const int tid  = threadIdx.x;
  const int lane = tid & 63;
  const int w    = tid >> 6;             // 0 or 1
  const int ucol = lane & 15;            // A-row (batch) index / N-col within tile
  const int kg   = (lane >> 4) & 3;
  const int b0   = blockIdx.x * 16;

  const int u0 = 32 * w + ucol;          // tile 0 unit (0-15 / 32-47: all real)
  const int u1 = 32 * w + 16 + ucol;     // tile 1 unit (16-31 real / 48-63 mixed)
  const float wfc0 = (u0 < HID) ? W_fc[u0] : 0.f;
  const float wfc1 = (u1 < HID) ? W_fc[u1] : 0.f;

  // ---- augmented B fragments, per N-tile (built once, pinned) ----
  short8 Bh[2][3][2], Bl[2][3][2];       // [tile][gate r/z/nh][frag]
  short8 Bch[2], Bcl[2];                 // n-gate x-part (frag1)
#pragma unroll
  for (int T = 0; T < 2; ++T) {
    const int u = 32 * w + 16 * T + ucol;
    const bool uv = (u < HID);
#pragma unroll
    for (int g = 0; g < 3; ++g) {
#pragma unroll
      for (int f = 0; f < 2; ++f) {
        union { short a[8]; short8 s; } ph, pl;
#pragma unroll
        for (int e = 0; e < 8; ++e) {
          const int k = 32 * f + 8 * kg + e;
          float v = 0.f;
          if (uv) {
            if (k < HID) v = W_hh[(g * 50 + u) * HID + k];
            else if (g < 2) {
              if (k <= 52)      v = W_ih[(g * 50 + u) * 3 + (k - 50)];
              else if (k == 53) v = b_ih[g * 50 + u] + b_hh[g * 50 + u];
              else if (k <= 56) v = W_ih[(g * 50 + u) * 3 + (k - 54)];
            } else {
              if (k == 53)      v = b_hh[100 + u];
            }
          }
          const unsigned short hi = bf16hi(v);
          const unsigned short lo = bf16hi(v - bf16tof(hi));
          ph.a[e] = (short)hi; pl.a[e] = (short)lo;
        }
        Bh[T][g][f] = ph.s; Bl[T][g][f] = pl.s;
      }
    }
    {
      union { short a[8]; short8 s; } ph, pl;
#pragma unroll
      for (int e = 0; e < 8; ++e) {
        const int k = 32 + 8 * kg + e;
        float v = 0.f;
        if (uv) {
          if (k >= 50 && k <= 52)      v = W_ih[(100 + u) * 3 + (k - 50)];
          else if (k == 53)            v = b_ih[100 + u];
          else if (k >= 54 && k <= 56) v = W_ih[(100 + u) * 3 + (k - 54)];
        }
        const unsigned short hi = bf16hi(v);
        const unsigned short lo = bf16hi(v - bf16tof(hi));
        ph.a[e] = (short)hi; pl.a[e] = (short)lo;
      }
      Bch[T] = ph.s; Bcl[T] = pl.s;
    }
  }
  // pin: volatile asm cannot be sunk/duplicated -> construction stays pre-loop
#pragma unroll
  for (int T = 0; T < 2; ++T) {
#pragma unroll
    for (int g = 0; g < 3; ++g) {
#pragma unroll
      for (int f = 0; f < 2; ++f) {
        asm volatile("" : "+v"(Bh[T][g][f]), "+v"(Bl[T][g][f]));
      }
    }
    asm volatile("" : "+v"(Bch[T]), "+v"(Bcl[T]));
  }

  // ---- init: zero both planes, seed x(0) + 1.0 into plane 0 ----
  ((float4*)hbuf)[tid]       = make_float4(0.f, 0.f, 0.f, 0.f);
  ((float4*)hbuf)[tid + 128] = make_float4(0.f, 0.f, 0.f, 0.f);
  __syncthreads();
  if (tid < 64) {
    const int m = tid & 15, c = tid >> 4;   // c = 0..3
    char* p0 = hbuf + m * 128;
    const int xr = (m & 7) << 4;
    if (c == 3) {
      *(unsigned short*)(p0 + ((2 * 53) ^ xr)) = 0x3F80;  // 1.0 bf16
    } else {
      const float xv = x[(size_t)(b0 + m) * (T_LEN * 3) + c];
      const unsigned short hi = bf16hi(xv);
      *(unsigned short*)(p0 + ((2 * (50 + c)) ^ xr)) = hi;
      *(unsigned short*)(p0 + ((2 * (54 + c)) ^ xr)) = bf16hi(xv - bf16tof(hi));
    }
  }

  float h0[4] = {0.f, 0.f, 0.f, 0.f};
  float h1[4] = {0.f, 0.f, 0.f, 0.f};
  const int arow = ucol * 128;
  const int axr  = (ucol & 7) << 4;
  const floatx4 z4 = {0.f, 0.f, 0.f, 0.f};

  // store offsets
  int hoff0[4], hoff1[4];
#pragma unroll
  for (int r = 0; r < 4; ++r) {
    const int m = 4 * kg + r;
    const int xr2 = (m & 7) << 4;
    hoff0[r] = m * 128 + ((2 * u0) ^ xr2);
    hoff1[r] = m * 128 + ((2 * u1) ^ xr2);
  }
  // wave-1 tile-1 x-duty: ucol 2..4 -> x_hi(ucol-2) ; 5 -> 1.0 ; 6..8 -> x_lo(ucol-6)
  int xc = (ucol >= 6) ? (ucol - 6) : (ucol - 2);
  xc = xc < 0 ? 0 : (xc > 2 ? 2 : xc);
  const int xcol   = (ucol >= 6) ? (54 + xc) : (ucol == 5 ? 53 : 50 + xc);
  const bool isOne = (ucol == 5);
  const bool isHi  = (ucol >= 2 && ucol <= 4);
  const bool isH1  = (ucol < 2);          // units 48,49 = real h
  int soff[4], xroff[4];
#pragma unroll
  for (int r = 0; r < 4; ++r) {
    const int m = 4 * kg + r;
    soff[r]  = isH1 ? hoff1[r] : (m * 128 + ((2 * xcol) ^ ((m & 7) << 4)));
    xroff[r] = xc * 64 + m * 4;
  }

  for (int tc = 0; tc < 8; ++tc) {
    // ---- stage x for t = tc*64+1 .. +64 (i = 0..63), layout [i][c][m16] ----
    {
      const int sm = tid >> 3, seg = tid & 7;    // 8 threads/batch, 24 floats each
      const float* xb = x + (size_t)(b0 + sm) * (T_LEN * 3) + tc * 192 + 3 + seg * 24;
      float vv[24];
      if (tc == 7 && seg == 7) {
#pragma unroll
        for (int j = 0; j < 24; ++j) vv[j] = (j < 21) ? xb[j] : 0.f;  // t=512 pad
      } else {
#pragma unroll
        for (int q = 0; q < 6; ++q) {
          const float4 v = *(const float4*)(xb + 4 * q);
          vv[4*q] = v.x; vv[4*q+1] = v.y; vv[4*q+2] = v.z; vv[4*q+3] = v.w;
        }
      }
#pragma unroll
      for (int jj = 0; jj < 24; ++jj) {
        const int i = seg * 24 + jj;
        *(float*)(xs + (i / 3) * 192 + (i % 3) * 64 + sm * 4) = vv[jj];
      }
    }
    __syncthreads();

#pragma unroll 2
    for (int s = 0; s < 64; ++s) {
      const int par = s & 1;
      const char* rp = hbuf + par * 2048;
      char*       wp = hbuf + (par ^ 1) * 2048;

      // A-frags shared by both N-tiles
      const short8 A0 = *(const short8*)(rp + arow + ((16 * kg)      ^ axr));
      const short8 A1 = *(const short8*)(rp + arow + ((16 * kg + 64) ^ axr));

      unsigned short hb0[4], hb1[4];
#pragma unroll
      for (int T = 0; T < 2; ++T) {
        floatx4 r1 = __builtin_amdgcn_mfma_f32_16x16x32_bf16(A0, Bh[T][0][0], z4, 0, 0, 0);
        r1 = __builtin_amdgcn_mfma_f32_16x16x32_bf16(A1, Bh[T][0][1], r1, 0, 0, 0);
        floatx4 r2 = __builtin_amdgcn_mfma_f32_16x16x32_bf16(A0, Bl[T][0][0], z4, 0, 0, 0);
        r2 = __builtin_amdgcn_mfma_f32_16x16x32_bf16(A1, Bl[T][0][1], r2, 0, 0, 0);
        floatx4 zA = __builtin_amdgcn_mfma_f32_16x16x32_bf16(A0, Bh[T][1][0], z4, 0, 0, 0);
        zA = __builtin_amdgcn_mfma_f32_16x16x32_bf16(A1, Bh[T][1][1], zA, 0, 0, 0);
        floatx4 zB = __builtin_amdgcn_mfma_f32_16x16x32_bf16(A0, Bl[T][1][0], z4, 0, 0, 0);
        zB = __builtin_amdgcn_mfma_f32_16x16x32_bf16(A1, Bl[T][1][1], zB, 0, 0, 0);
        floatx4 nA = __builtin_amdgcn_mfma_f32_16x16x32_bf16(A0, Bh[T][2][0], z4, 0, 0, 0);
        nA = __builtin_amdgcn_mfma_f32_16x16x32_bf16(A1, Bh[T][2][1], nA, 0, 0, 0);
        floatx4 nB = __builtin_amdgcn_mfma_f32_16x16x32_bf16(A0, Bl[T][2][0], z4, 0, 0, 0);
        nB = __builtin_amdgcn_mfma_f32_16x16x32_bf16(A1, Bl[T][2][1], nB, 0, 0, 0);
        floatx4 c1 = __builtin_amdgcn_mfma_f32_16x16x32_bf16(A1, Bch[T], z4, 0, 0, 0);
        floatx4 c2 = __builtin_amdgcn_mfma_f32_16x16x32_bf16(A1, Bcl[T], c1, 0, 0, 0);

        float*          hh = T ? h1  : h0;     // T compile-time (unrolled)
        unsigned short* hb = T ? hb1 : hb0;
#pragma unroll
        for (int r = 0; r < 4; ++r) {
          const float rr = sigm(r1[r] + r2[r]);
          const float zz = sigm(zA[r] + zB[r]);
          const float nv = fmaf(rr, nA[r] + nB[r], c2[r]);
          const float nn = tanh_f(nv);
          hh[r] = fmaf(zz, hh[r] - nn, nn);
          hb[r] = bf16hi(hh[r]);
        }
      }

      // stores: tile0 always real h; tile1 per wave
#pragma unroll
      for (int r = 0; r < 4; ++r)
        *(unsigned short*)(wp + hoff0[r]) = hb0[r];
      if (w == 0) {                            // wave-uniform branch
#pragma unroll
        for (int r = 0; r < 4; ++r)
          *(unsigned short*)(wp + hoff1[r]) = hb1[r];
      } else {
#pragma unroll
        for (int r = 0; r < 4; ++r) {
          const float xv = *(const float*)(xs + s * 192 + xroff[r]);
          const unsigned short hi = bf16hi(xv);
          const unsigned short lo = bf16hi(xv - bf16tof(hi));
          unsigned short val = isHi ? hi : lo;
          val = isOne ? (unsigned short)0x3F80 : val;
          val = isH1 ? hb1[r] : val;
          if (ucol <= 8)
            *(unsigned short*)(wp + soff[r]) = val;
        }
      }
      __syncthreads();
    }
  }

  // ---- FC epilogue: out[b] = sum_u h_u * W_fc[u] + b_fc ----
  float p[4];
#pragma unroll
  for (int r = 0; r < 4; ++r) p[r] = h0[r] * wfc0 + h1[r] * wfc1;
#pragma unroll
  for (int mask = 1; mask < 16; mask <<= 1) {
#pragma unroll
    for (int r = 0; r < 4; ++r) p[r] += __shfl_xor(p[r], mask);
  }
  if (ucol == 0) {
    *(float4*)((float*)lds + (w * 16 + kg * 4)) = make_float4(p[0], p[1], p[2], p[3]);
  }
  __syncthreads();
  if (tid < 16) {
    out[b0 + tid] = ((const float*)lds)[tid] + ((const float*)lds)[16 + tid] + b_fc[0];
  }
}

extern "C" void kernel_launch(void* const* d_in, const int* in_sizes, int n_in,
                              void* d_out, int out_size, void* d_ws, size_t ws_size,
                              hipStream_t stream) {
  const float* x    = (const float*)d_in[0];
  const float* W_ih = (const float*)d_in[1];
  const float* W_hh = (const float*)d_in[2];
  const float* b_ih = (const float*)d_in[3];
  const float* b_hh = (const float*)d_in[4];
  const float* W_fc = (const float*)d_in[5];
  const float* b_fc = (const float*)d_in[6];
  float* out = (float*)d_out;

  dim3 grid(NBATCH / 16);   // 256 blocks x 16 batches; 2-wave exchange groups
  dim3 block(128);
  gru_mfma_kernel<<<grid, block, 0, stream>>>(x, W_ih, W_hh, b_ih, b_hh, W_fc, b_fc, out);
}

// Round 13
// 457.259 us; speedup vs baseline: 1.0370x; 1.0370x over previous
//
#include <hip/hip_runtime.h>
#include <hip/hip_bf16.h>

#define T_LEN 512
#define HID 50
#define NBATCH 4096

using short8  = __attribute__((ext_vector_type(8))) short;
using floatx4 = __attribute__((ext_vector_type(4))) float;

__device__ __forceinline__ float sigm(float v) {
  return __builtin_amdgcn_rcpf(1.0f + __builtin_amdgcn_exp2f(-1.442695041f * v));
}
__device__ __forceinline__ float tanh_f(float v) {
  return 1.0f - 2.0f * __builtin_amdgcn_rcpf(1.0f + __builtin_amdgcn_exp2f(2.885390082f * v));
}
__device__ __forceinline__ unsigned short bf16hi(float v) {
  __hip_bfloat16 b = __float2bfloat16(v);
  return *(unsigned short*)&b;
}
__device__ __forceinline__ float bf16tof(unsigned short u) {
  return __uint_as_float((unsigned int)u << 16);
}

// TWO independent 8-batch GRU chains per block (group g = 0,1), same weights.
// h plane (per group, per parity): 8 rows (m=batch) x 64 bf16 cols, row 128 B,
// XOR swizzle (m<<4).  Cols: 0..49 h_hi ; 50..52 x_hi ; 53 = 1.0 ; 54..56 x_lo.
// k-bijection (A reads and B build): k = 32*f + 8*kg + e.
// M=8: A-frag reads row (ucol&7) -> C rows 8-15 duplicate 0-7, stores masked kg<2.
__global__ __launch_bounds__(256, 1)
void gru_mfma_kernel(const float* __restrict__ x,
                     const float* __restrict__ W_ih,
                     const float* __restrict__ W_hh,
                     const float* __restrict__ b_ih,
                     const float* __restrict__ b_hh,
                     const float* __restrict__ W_fc,
                     const float* __restrict__ b_fc,
                     float* __restrict__ out) {
  // LDS: [0,12288) x-chunk [i64][c3][m16] f32 ; [12288,16384) 4 planes (g0p0,g0p1,g1p0,g1p1)
  __shared__ alignas(16) unsigned char lds[16384];
  char* xs   = (char*)lds;
  char* hbuf = (char*)lds + 12288;

  const int tid  = threadIdx.x;
  const int lane = tid & 63;
  const int w    = tid >> 6;             // wave id: owns units 16w..16w+15
  const int ucol = lane & 15;
  const int kg   = (lane >> 4) & 3;
  const int b0   = blockIdx.x * 16;      // group0: b0..b0+7, group1: b0+8..b0+15
  const int u    = 16 * w + ucol;
  const bool uv  = (u < HID);

  const float wfc = uv ? W_fc[u] : 0.f;

  // ---- augmented B fragments (shared by both groups) ----
  short8 Bh[3][2], Bl[3][2];
  short8 Bch, Bcl;
#pragma unroll
  for (int g = 0; g < 3; ++g) {
#pragma unroll
    for (int f = 0; f < 2; ++f) {
      union { short a[8]; short8 s; } ph, pl;
#pragma unroll
      for (int e = 0; e < 8; ++e) {
        const int k = 32 * f + 8 * kg + e;
        float v = 0.f;
        if (uv) {
          if (k < HID) v = W_hh[(g * 50 + u) * HID + k];
          else if (g < 2) {
            if (k <= 52)      v = W_ih[(g * 50 + u) * 3 + (k - 50)];
            else if (k == 53) v = b_ih[g * 50 + u] + b_hh[g * 50 + u];
            else if (k <= 56) v = W_ih[(g * 50 + u) * 3 + (k - 54)];
          } else {
            if (k == 53)      v = b_hh[100 + u];
          }
        }
        const unsigned short hi = bf16hi(v);
        const unsigned short lo = bf16hi(v - bf16tof(hi));
        ph.a[e] = (short)hi; pl.a[e] = (short)lo;
      }
      Bh[g][f] = ph.s; Bl[g][f] = pl.s;
    }
  }
  {
    union { short a[8]; short8 s; } ph, pl;
#pragma unroll
    for (int e = 0; e < 8; ++e) {
      const int k = 32 + 8 * kg + e;
      float v = 0.f;
      if (uv) {
        if (k >= 50 && k <= 52)      v = W_ih[(100 + u) * 3 + (k - 50)];
        else if (k == 53)            v = b_ih[100 + u];
        else if (k >= 54 && k <= 56) v = W_ih[(100 + u) * 3 + (k - 54)];
      }
      const unsigned short hi = bf16hi(v);
      const unsigned short lo = bf16hi(v - bf16tof(hi));
      ph.a[e] = (short)hi; pl.a[e] = (short)lo;
    }
    Bch = ph.s; Bcl = pl.s;
  }

  // ---- init: zero all 4 planes, seed x(0)+1.0 into plane(g,0) ----
  ((float4*)hbuf)[tid] = make_float4(0.f, 0.f, 0.f, 0.f);   // 256*16 = 4096 B
  __syncthreads();
  if (tid < 64) {
    const int g = tid >> 5, idx = tid & 31;
    const int m = idx & 7, c = idx >> 3;    // c = 0..3
    char* p0 = hbuf + g * 2048 + m * 128;
    const int xr = m << 4;
    if (c == 3) {
      *(unsigned short*)(p0 + ((2 * 53) ^ xr)) = 0x3F80;  // 1.0 bf16
    } else {
      const float xv = x[(size_t)(b0 + g * 8 + m) * (T_LEN * 3) + c];
      const unsigned short hi = bf16hi(xv);
      *(unsigned short*)(p0 + ((2 * (50 + c)) ^ xr)) = hi;
      *(unsigned short*)(p0 + ((2 * (54 + c)) ^ xr)) = bf16hi(xv - bf16tof(hi));
    }
  }

  float hA[4] = {0.f, 0.f, 0.f, 0.f};     // group 0: batch 4kg+r (kg<2 real)
  float hB[4] = {0.f, 0.f, 0.f, 0.f};     // group 1
  const int arow = (ucol & 7) * 128;
  const int axr  = (ucol & 7) << 4;
  const floatx4 z4 = {0.f, 0.f, 0.f, 0.f};

  // store offsets (plane-relative; only kg<2 used)
  int hoff[4];
#pragma unroll
  for (int r = 0; r < 4; ++r) {
    const int m = (4 * kg + r) & 7;
    hoff[r] = m * 128 + ((2 * u) ^ (m << 4));
  }
  // wave-3 x-duty: ucol 2..4 -> x_hi(ucol-2) ; 5 -> 1.0 ; 6..8 -> x_lo(ucol-6)
  int xc = (ucol >= 6) ? (ucol - 6) : (ucol - 2);
  xc = xc < 0 ? 0 : (xc > 2 ? 2 : xc);
  const int xcol   = (ucol >= 6) ? (54 + xc) : (ucol == 5 ? 53 : 50 + xc);
  const bool isOne = (ucol == 5);
  const bool isHi  = (ucol >= 2 && ucol <= 4);
  const bool isH1  = (ucol < 2);          // units 48,49 = real h
  int soff[4], xroff[4];
#pragma unroll
  for (int r = 0; r < 4; ++r) {
    const int m = (4 * kg + r) & 7;
    soff[r]  = isH1 ? hoff[r] : (m * 128 + ((2 * xcol) ^ (m << 4)));
    xroff[r] = xc * 64 + m * 4;           // + g*32 + s*192 at use
  }

  for (int tc = 0; tc < 8; ++tc) {
    // ---- stage x for t = tc*64+1 .. +64 (i = 0..63), layout [i][c][m16] ----
    {
      const int sm = tid >> 4, seg = tid & 15;
      const float* xb = x + (size_t)(b0 + sm) * (T_LEN * 3) + tc * 192 + 3 + seg * 12;
      float vv[12];
      if (tc == 7 && seg == 15) {
#pragma unroll
        for (int j = 0; j < 12; ++j) vv[j] = (j < 9) ? xb[j] : 0.f;  // t=512 pad
      } else {
        const float4 v0 = *(const float4*)(xb + 0);
        const float4 v1 = *(const float4*)(xb + 4);
        const float4 v2 = *(const float4*)(xb + 8);
        vv[0]=v0.x; vv[1]=v0.y; vv[2]=v0.z; vv[3]=v0.w;
        vv[4]=v1.x; vv[5]=v1.y; vv[6]=v1.z; vv[7]=v1.w;
        vv[8]=v2.x; vv[9]=v2.y; vv[10]=v2.z; vv[11]=v2.w;
      }
#pragma unroll
      for (int jj = 0; jj < 12; ++jj) {
        const int i = seg * 12 + jj;
        *(float*)(xs + (i / 3) * 192 + (i % 3) * 64 + sm * 4) = vv[jj];
      }
    }
    __syncthreads();

#pragma unroll 2
    for (int s = 0; s < 64; ++s) {
      const int par = s & 1;
      // planes: g*2048 + par*1024
      const char* rp0 = hbuf + par * 1024;
      const char* rp1 = hbuf + 2048 + par * 1024;
      char*       wp0 = hbuf + (par ^ 1) * 1024;
      char*       wp1 = hbuf + 2048 + (par ^ 1) * 1024;

      // ---- both groups' A-frags up front (independent loads) ----
      const short8 A00 = *(const short8*)(rp0 + arow + ((16 * kg)      ^ axr));
      const short8 A01 = *(const short8*)(rp0 + arow + ((16 * kg + 64) ^ axr));
      const short8 A10 = *(const short8*)(rp1 + arow + ((16 * kg)      ^ axr));
      const short8 A11 = *(const short8*)(rp1 + arow + ((16 * kg + 64) ^ axr));

      // ---- group 0 MFMA (2+2-deep parallel chains) ----
      floatx4 r1a = __builtin_amdgcn_mfma_f32_16x16x32_bf16(A00, Bh[0][0], z4, 0, 0, 0);
      r1a = __builtin_amdgcn_mfma_f32_16x16x32_bf16(A01, Bh[0][1], r1a, 0, 0, 0);
      floatx4 r2a = __builtin_amdgcn_mfma_f32_16x16x32_bf16(A00, Bl[0][0], z4, 0, 0, 0);
      r2a = __builtin_amdgcn_mfma_f32_16x16x32_bf16(A01, Bl[0][1], r2a, 0, 0, 0);
      floatx4 zAa = __builtin_amdgcn_mfma_f32_16x16x32_bf16(A00, Bh[1][0], z4, 0, 0, 0);
      zAa = __builtin_amdgcn_mfma_f32_16x16x32_bf16(A01, Bh[1][1], zAa, 0, 0, 0);
      floatx4 zBa = __builtin_amdgcn_mfma_f32_16x16x32_bf16(A00, Bl[1][0], z4, 0, 0, 0);
      zBa = __builtin_amdgcn_mfma_f32_16x16x32_bf16(A01, Bl[1][1], zBa, 0, 0, 0);
      floatx4 nAa = __builtin_amdgcn_mfma_f32_16x16x32_bf16(A00, Bh[2][0], z4, 0, 0, 0);
      nAa = __builtin_amdgcn_mfma_f32_16x16x32_bf16(A01, Bh[2][1], nAa, 0, 0, 0);
      floatx4 nBa = __builtin_amdgcn_mfma_f32_16x16x32_bf16(A00, Bl[2][0], z4, 0, 0, 0);
      nBa = __builtin_amdgcn_mfma_f32_16x16x32_bf16(A01, Bl[2][1], nBa, 0, 0, 0);
      floatx4 cCa = __builtin_amdgcn_mfma_f32_16x16x32_bf16(A01, Bch, z4, 0, 0, 0);
      cCa = __builtin_amdgcn_mfma_f32_16x16x32_bf16(A01, Bcl, cCa, 0, 0, 0);

      // ---- group 1 MFMA (independent chain) ----
      floatx4 r1b = __builtin_amdgcn_mfma_f32_16x16x32_bf16(A10, Bh[0][0], z4, 0, 0, 0);
      r1b = __builtin_amdgcn_mfma_f32_16x16x32_bf16(A11, Bh[0][1], r1b, 0, 0, 0);
      floatx4 r2b = __builtin_amdgcn_mfma_f32_16x16x32_bf16(A10, Bl[0][0], z4, 0, 0, 0);
      r2b = __builtin_amdgcn_mfma_f32_16x16x32_bf16(A11, Bl[0][1], r2b, 0, 0, 0);
      floatx4 zAb = __builtin_amdgcn_mfma_f32_16x16x32_bf16(A10, Bh[1][0], z4, 0, 0, 0);
      zAb = __builtin_amdgcn_mfma_f32_16x16x32_bf16(A11, Bh[1][1], zAb, 0, 0, 0);
      floatx4 zBb = __builtin_amdgcn_mfma_f32_16x16x32_bf16(A10, Bl[1][0], z4, 0, 0, 0);
      zBb = __builtin_amdgcn_mfma_f32_16x16x32_bf16(A11, Bl[1][1], zBb, 0, 0, 0);
      floatx4 nAb = __builtin_amdgcn_mfma_f32_16x16x32_bf16(A10, Bh[2][0], z4, 0, 0, 0);
      nAb = __builtin_amdgcn_mfma_f32_16x16x32_bf16(A11, Bh[2][1], nAb, 0, 0, 0);
      floatx4 nBb = __builtin_amdgcn_mfma_f32_16x16x32_bf16(A10, Bl[2][0], z4, 0, 0, 0);
      nBb = __builtin_amdgcn_mfma_f32_16x16x32_bf16(A11, Bl[2][1], nBb, 0, 0, 0);
      floatx4 cCb = __builtin_amdgcn_mfma_f32_16x16x32_bf16(A11, Bch, z4, 0, 0, 0);
      cCb = __builtin_amdgcn_mfma_f32_16x16x32_bf16(A11, Bcl, cCb, 0, 0, 0);

      // ---- activations (two independent chains) ----
      unsigned short hbA[4], hbB[4];
#pragma unroll
      for (int r = 0; r < 4; ++r) {
        const float rr = sigm(r1a[r] + r2a[r]);
        const float zz = sigm(zAa[r] + zBa[r]);
        const float nn = tanh_f(fmaf(rr, nAa[r] + nBa[r], cCa[r]));
        hA[r] = fmaf(zz, hA[r] - nn, nn);
        hbA[r] = bf16hi(hA[r]);
      }
#pragma unroll
      for (int r = 0; r < 4; ++r) {
        const float rr = sigm(r1b[r] + r2b[r]);
        const float zz = sigm(zAb[r] + zBb[r]);
        const float nn = tanh_f(fmaf(rr, nAb[r] + nBb[r], cCb[r]));
        hB[r] = fmaf(zz, hB[r] - nn, nn);
        hbB[r] = bf16hi(hB[r]);
      }

      // ---- stores (rows 0-7 only: kg<2) ----
      if (w < 3) {
        if (kg < 2) {
#pragma unroll
          for (int r = 0; r < 4; ++r) {
            *(unsigned short*)(wp0 + hoff[r]) = hbA[r];
            *(unsigned short*)(wp1 + hoff[r]) = hbB[r];
          }
        }
      } else {
        if (kg < 2 && ucol <= 8) {
#pragma unroll
          for (int r = 0; r < 4; ++r) {
            const float xvA = *(const float*)(xs + s * 192 + xroff[r]);
            const float xvB = *(const float*)(xs + s * 192 + 32 + xroff[r]);
            const unsigned short hiA = bf16hi(xvA);
            const unsigned short hiB = bf16hi(xvB);
            unsigned short vA = isHi ? hiA : bf16hi(xvA - bf16tof(hiA));
            unsigned short vB = isHi ? hiB : bf16hi(xvB - bf16tof(hiB));
            vA = isOne ? (unsigned short)0x3F80 : vA;
            vB = isOne ? (unsigned short)0x3F80 : vB;
            vA = isH1 ? hbA[r] : vA;
            vB = isH1 ? hbB[r] : vB;
            *(unsigned short*)(wp0 + soff[r]) = vA;
            *(unsigned short*)(wp1 + soff[r]) = vB;
          }
        }
      }
      __syncthreads();
    }
  }

  // ---- FC epilogue: out[b0 + g*8 + m] ----
  float pA[4], pB[4];
#pragma unroll
  for (int r = 0; r < 4; ++r) { pA[r] = hA[r] * wfc; pB[r] = hB[r] * wfc; }
#pragma unroll
  for (int mask = 1; mask < 16; mask <<= 1) {
#pragma unroll
    for (int r = 0; r < 4; ++r) {
      pA[r] += __shfl_xor(pA[r], mask);
      pB[r] += __shfl_xor(pB[r], mask);
    }
  }
  if (ucol == 0 && kg < 2) {
    float* sl = (float*)lds + w * 16;
    *(float4*)(sl + kg * 4)     = make_float4(pA[0], pA[1], pA[2], pA[3]);
    *(float4*)(sl + 8 + kg * 4) = make_float4(pB[0], pB[1], pB[2], pB[3]);
  }
  __syncthreads();
  if (tid < 16) {
    float ssum = 0.f;
#pragma unroll
    for (int ww = 0; ww < 4; ++ww) ssum += ((const float*)lds)[ww * 16 + tid];
    out[b0 + tid] = ssum + b_fc[0];
  }
}

extern "C" void kernel_launch(void* const* d_in, const int* in_sizes, int n_in,
                              void* d_out, int out_size, void* d_ws, size_t ws_size,
                              hipStream_t stream) {
  const float* x    = (const float*)d_in[0];
  const float* W_ih = (const float*)d_in[1];
  const float* W_hh = (const float*)d_in[2];
  const float* b_ih = (const float*)d_in[3];
  const float* b_hh = (const float*)d_in[4];
  const float* W_fc = (const float*)d_in[5];
  const float* b_fc = (const float*)d_in[6];
  float* out = (float*)d_out;

  dim3 grid(NBATCH / 16);   // 256 blocks x (2 groups x 8 batches); 4 waves
  dim3 block(256);
  gru_mfma_kernel<<<grid, block, 0, stream>>>(x, W_ih, W_hh, b_ih, b_hh, W_fc, b_fc, out);
}

// Round 14
// 231.259 us; speedup vs baseline: 2.0504x; 1.9773x over previous
//
#include <hip/hip_runtime.h>
#include <hip/hip_bf16.h>

#define T_LEN 512
#define HID 50
#define NBATCH 4096

using short8  = __attribute__((ext_vector_type(8))) short;
using floatx4 = __attribute__((ext_vector_type(4))) float;

__device__ __forceinline__ float sigm(float v) {
  return __builtin_amdgcn_rcpf(1.0f + __builtin_amdgcn_exp2f(-1.442695041f * v));
}
__device__ __forceinline__ float tanh_f(float v) {
  return 1.0f - 2.0f * __builtin_amdgcn_rcpf(1.0f + __builtin_amdgcn_exp2f(2.885390082f * v));
}

// h plane: 16 rows (m=batch) x 64 bf16 (u), row = 128 B, XOR swizzle ((row&7)<<4).
// k-bijection (A reads and B build): k = 32*f + 8*kg + e  (f=frag, e=0..7)
// -> A-fragment (f) = ONE contiguous 16B read at byte (64f + 16kg) ^ xr.
__device__ __forceinline__ short8 afrag(const char* plane, int rowoff, int off16) {
  return *(const short8*)(plane + rowoff + off16);
}

__global__ __launch_bounds__(256, 1)
void gru_mfma_kernel(const float* __restrict__ x,
                     const float* __restrict__ W_ih,
                     const float* __restrict__ W_hh,
                     const float* __restrict__ b_ih,
                     const float* __restrict__ b_hh,
                     const float* __restrict__ W_fc,
                     const float* __restrict__ b_fc,
                     float* __restrict__ out) {
  // LDS: [0,12288) x-chunk [t64][c3][m16] f32 ; [12288,14336) h buf0 ; [14336,16384) h buf1
  __shared__ alignas(16) unsigned char lds[16384];
  char* xs   = (char*)lds;
  char* hbuf = (char*)lds + 12288;

  const int tid  = threadIdx.x;
  const int lane = tid & 63;
  const int w    = tid >> 6;          // wave id: owns units 16w..16w+15
  const int ucol = lane & 15;         // N-col within tile / A-row (batch) index
  const int kg   = (lane >> 4) & 3;   // k-group (slot) for A/B frags; m-group for C rows
  const int b0   = blockIdx.x * 16;
  const int u    = 16 * w + ucol;     // this lane's hidden unit
  const bool uv  = (u < HID);

  // ---- per-lane bias / input-weight constants ----
  const float c_r  = uv ? (b_ih[u] + b_hh[u]) : 0.f;
  const float c_z  = uv ? (b_ih[50 + u] + b_hh[50 + u]) : 0.f;
  const float c_ni = uv ? b_ih[100 + u] : 0.f;
  const float c_nh = uv ? b_hh[100 + u] : 0.f;
  float u_r[3], u_z[3], u_n[3];
#pragma unroll
  for (int c = 0; c < 3; ++c) {
    u_r[c] = uv ? W_ih[u * 3 + c] : 0.f;
    u_z[c] = uv ? W_ih[(50 + u) * 3 + c] : 0.f;
    u_n[c] = uv ? W_ih[(100 + u) * 3 + c] : 0.f;
  }
  const float wfc = uv ? W_fc[u] : 0.f;

  // ---- persistent B-fragments (W_hh): hi for all gates, lo for n only ----
  short8 Bh[3][2];          // gates 0=r, 1=z, 2=n  (hi part)
  short8 Bnl[2];            // n-gate lo part only (tanh path: slope 1, keep precision)
#pragma unroll
  for (int g = 0; g < 3; ++g) {
    const int row = uv ? (g * 50 + u) : 0;
    const float* Wrow = W_hh + row * HID;
#pragma unroll
    for (int f = 0; f < 2; ++f) {
      union { short a[8]; short8 s; } ph, pl;
#pragma unroll
      for (int e = 0; e < 8; ++e) {
        const int k = 32 * f + 8 * kg + e;
        const float v = (uv && k < HID) ? Wrow[k] : 0.f;
        __hip_bfloat16 bh = __float2bfloat16(v);
        const float vh = __bfloat162float(bh);
        __hip_bfloat16 bl = __float2bfloat16(v - vh);
        ph.a[e] = *(short*)&bh;
        pl.a[e] = *(short*)&bl;
      }
      Bh[g][f] = ph.s;
      if (g == 2) Bnl[f] = pl.s;
    }
  }

  // zero both h planes (2 x 2048 B = 4096 B = 256 threads x 16 B)
  ((float4*)hbuf)[tid] = make_float4(0.f, 0.f, 0.f, 0.f);

  float h[4] = {0.f, 0.f, 0.f, 0.f};           // unit u, batches 4*kg..4*kg+3

  const int arow = ucol * 128;                  // A row offset (batch = ucol)
  const int axr  = (ucol & 7) << 4;             // A-read XOR
  const floatx4 z4 = {0.f, 0.f, 0.f, 0.f};

  for (int tc = 0; tc < 8; ++tc) {
    // ---- stage x chunk: 16 batches x 64 t x 3 c -> LDS [t][c][m] ----
    {
      const int sm = tid >> 4, seg = tid & 15;
      const float* xb = x + (size_t)(b0 + sm) * (T_LEN * 3) + tc * 192 + seg * 12;
      const float4 v0 = *(const float4*)(xb + 0);
      const float4 v1 = *(const float4*)(xb + 4);
      const float4 v2 = *(const float4*)(xb + 8);
      const float vv[12] = {v0.x, v0.y, v0.z, v0.w, v1.x, v1.y, v1.z, v1.w, v2.x, v2.y, v2.z, v2.w};
#pragma unroll
      for (int jj = 0; jj < 12; ++jj) {
        const int i = seg * 12 + jj;
        *(float*)(xs + (i / 3) * 192 + (i % 3) * 64 + sm * 4) = vv[jj];
      }
    }
    __syncthreads();

#pragma unroll 2
    for (int s = 0; s < 64; ++s) {
      const int par = s & 1;
      const char* rp = hbuf + par * 2048;
      char*       wp = hbuf + (par ^ 1) * 2048;

      // x reads (barrier-independent)
      const float4 xv0 = *(const float4*)(xs + s * 192 + 0 * 64 + kg * 16);
      const float4 xv1 = *(const float4*)(xs + s * 192 + 1 * 64 + kg * 16);
      const float4 xv2 = *(const float4*)(xs + s * 192 + 2 * 64 + kg * 16);

      // A-fragments: 2 x ds_read_b128
      const short8 A0 = afrag(rp, arow, (16 * kg +  0) ^ axr);
      const short8 A1 = afrag(rp, arow, (16 * kg + 64) ^ axr);

      // MFMA: r,z hi-only (2-deep); n hi + lo (two 2-deep parallel chains)
      floatx4 aR = __builtin_amdgcn_mfma_f32_16x16x32_bf16(A0, Bh[0][0], z4, 0, 0, 0);
      aR = __builtin_amdgcn_mfma_f32_16x16x32_bf16(A1, Bh[0][1], aR, 0, 0, 0);
      floatx4 aZ = __builtin_amdgcn_mfma_f32_16x16x32_bf16(A0, Bh[1][0], z4, 0, 0, 0);
      aZ = __builtin_amdgcn_mfma_f32_16x16x32_bf16(A1, Bh[1][1], aZ, 0, 0, 0);
      floatx4 nA = __builtin_amdgcn_mfma_f32_16x16x32_bf16(A0, Bh[2][0], z4, 0, 0, 0);
      nA = __builtin_amdgcn_mfma_f32_16x16x32_bf16(A1, Bh[2][1], nA, 0, 0, 0);
      floatx4 nB = __builtin_amdgcn_mfma_f32_16x16x32_bf16(A0, Bnl[0], z4, 0, 0, 0);
      nB = __builtin_amdgcn_mfma_f32_16x16x32_bf16(A1, Bnl[1], nB, 0, 0, 0);

      const float xa[4]  = {xv0.x, xv0.y, xv0.z, xv0.w};
      const float xb_[4] = {xv1.x, xv1.y, xv1.z, xv1.w};
      const float xc[4]  = {xv2.x, xv2.y, xv2.z, xv2.w};
#pragma unroll
      for (int r = 0; r < 4; ++r) {
        const float x0 = xa[r], x1 = xb_[r], x2 = xc[r];
        const float gr = fmaf(x0, u_r[0], fmaf(x1, u_r[1], fmaf(x2, u_r[2], c_r)));
        const float gz = fmaf(x0, u_z[0], fmaf(x1, u_z[1], fmaf(x2, u_z[2], c_z)));
        const float gn = fmaf(x0, u_n[0], fmaf(x1, u_n[1], fmaf(x2, u_n[2], c_ni)));
        const float rr = sigm(aR[r] + gr);
        const float zz = sigm(aZ[r] + gz);
        const float nv = gn + rr * (nA[r] + nB[r] + c_nh);
        const float nn = tanh_f(nv);
        const float hn = nn + zz * (h[r] - nn);
        h[r] = hn;
        __hip_bfloat16 bh = __float2bfloat16(hn);
        const int mrow = 4 * kg + r;
        *(unsigned short*)(wp + mrow * 128 + ((2 * u) ^ ((mrow & 7) << 4))) =
            *(const unsigned short*)&bh;
      }
      __syncthreads();
    }
  }

  // ---- FC epilogue ----
  float p[4];
#pragma unroll
  for (int r = 0; r < 4; ++r) p[r] = h[r] * wfc;
#pragma unroll
  for (int mask = 1; mask < 16; mask <<= 1) {
#pragma unroll
    for (int r = 0; r < 4; ++r) p[r] += __shfl_xor(p[r], mask);
  }
  if (ucol == 0) {
    *(float4*)(lds + (w * 16 + 4 * kg) * 4) = make_float4(p[0], p[1], p[2], p[3]);
  }
  __syncthreads();
  if (tid < 16) {
    float ssum = 0.f;
#pragma unroll
    for (int ww = 0; ww < 4; ++ww) ssum += *(const float*)(lds + (ww * 16 + tid) * 4);
    out[b0 + tid] = ssum + b_fc[0];
  }
}

extern "C" void kernel_launch(void* const* d_in, const int* in_sizes, int n_in,
                              void* d_out, int out_size, void* d_ws, size_t ws_size,
                              hipStream_t stream) {
  const float* x    = (const float*)d_in[0];
  const float* W_ih = (const float*)d_in[1];
  const float* W_hh = (const float*)d_in[2];
  const float* b_ih = (const float*)d_in[3];
  const float* b_hh = (const float*)d_in[4];
  const float* W_fc = (const float*)d_in[5];
  const float* b_fc = (const float*)d_in[6];
  float* out = (float*)d_out;

  dim3 grid(NBATCH / 16);   // 256 blocks x 16 batches; 4 waves = 4 unit-tiles
  dim3 block(256);
  gru_mfma_kernel<<<grid, block, 0, stream>>>(x, W_ih, W_hh, b_ih, b_hh, W_fc, b_fc, out);
}

// Round 15
// 222.055 us; speedup vs baseline: 2.1354x; 1.0414x over previous
//
#include <hip/hip_runtime.h>
#include <hip/hip_bf16.h>

#define T_LEN 512
#define HID 50
#define NBATCH 4096

using short8  = __attribute__((ext_vector_type(8))) short;
using floatx4 = __attribute__((ext_vector_type(4))) float;

__device__ __forceinline__ float sigm(float v) {
  return __builtin_amdgcn_rcpf(1.0f + __builtin_amdgcn_exp2f(-1.442695041f * v));
}
__device__ __forceinline__ float tanh_f(float v) {
  return 1.0f - 2.0f * __builtin_amdgcn_rcpf(1.0f + __builtin_amdgcn_exp2f(2.885390082f * v));
}

// h plane: 16 rows (m=batch) x 64 bf16 (u), row = 128 B, XOR swizzle ((row&7)<<4).
// k-bijection (A reads and B build): k = 32*f + 8*kg + e  (f=frag, e=0..7)
// -> A-fragment (f) = ONE contiguous 16B read at byte (64f + 16kg) ^ xr.
__device__ __forceinline__ short8 afrag(const char* plane, int rowoff, int off16) {
  return *(const short8*)(plane + rowoff + off16);
}

__global__ __launch_bounds__(256, 1)
void gru_mfma_kernel(const float* __restrict__ x,
                     const float* __restrict__ W_ih,
                     const float* __restrict__ W_hh,
                     const float* __restrict__ b_ih,
                     const float* __restrict__ b_hh,
                     const float* __restrict__ W_fc,
                     const float* __restrict__ b_fc,
                     float* __restrict__ out) {
  // LDS: [0,12288) x-chunk [t64][c3][m16] f32 ; [12288,14336) h buf0 ; [14336,16384) h buf1
  __shared__ alignas(16) unsigned char lds[16384];
  char* xs   = (char*)lds;
  char* hbuf = (char*)lds + 12288;

  const int tid  = threadIdx.x;
  const int lane = tid & 63;
  const int w    = tid >> 6;          // wave id: owns units 16w..16w+15
  const int ucol = lane & 15;         // N-col within tile / A-row (batch) index
  const int kg   = (lane >> 4) & 3;   // k-group (slot) for A/B frags; m-group for C rows
  const int b0   = blockIdx.x * 16;
  const int u    = 16 * w + ucol;     // this lane's hidden unit
  const bool uv  = (u < HID);

  // ---- per-lane bias / input-weight constants ----
  const float c_r  = uv ? (b_ih[u] + b_hh[u]) : 0.f;
  const float c_z  = uv ? (b_ih[50 + u] + b_hh[50 + u]) : 0.f;
  const float c_ni = uv ? b_ih[100 + u] : 0.f;
  const float c_nh = uv ? b_hh[100 + u] : 0.f;
  float u_r[3], u_z[3], u_n[3];
#pragma unroll
  for (int c = 0; c < 3; ++c) {
    u_r[c] = uv ? W_ih[u * 3 + c] : 0.f;
    u_z[c] = uv ? W_ih[(50 + u) * 3 + c] : 0.f;
    u_n[c] = uv ? W_ih[(100 + u) * 3 + c] : 0.f;
  }
  const float wfc = uv ? W_fc[u] : 0.f;

  // ---- persistent B-fragments (W_hh): plain bf16 (hi), all three gates ----
  short8 Bh[3][2];          // gates 0=r, 1=z, 2=n
#pragma unroll
  for (int g = 0; g < 3; ++g) {
    const int row = uv ? (g * 50 + u) : 0;
    const float* Wrow = W_hh + row * HID;
#pragma unroll
    for (int f = 0; f < 2; ++f) {
      union { short a[8]; short8 s; } ph;
#pragma unroll
      for (int e = 0; e < 8; ++e) {
        const int k = 32 * f + 8 * kg + e;
        const float v = (uv && k < HID) ? Wrow[k] : 0.f;
        __hip_bfloat16 bh = __float2bfloat16(v);
        ph.a[e] = *(short*)&bh;
      }
      Bh[g][f] = ph.s;
    }
  }

  // zero both h planes (2 x 2048 B = 4096 B = 256 threads x 16 B)
  ((float4*)hbuf)[tid] = make_float4(0.f, 0.f, 0.f, 0.f);

  float h[4] = {0.f, 0.f, 0.f, 0.f};           // unit u, batches 4*kg..4*kg+3

  const int arow = ucol * 128;                  // A row offset (batch = ucol)
  const int axr  = (ucol & 7) << 4;             // A-read XOR
  const floatx4 z4 = {0.f, 0.f, 0.f, 0.f};

  for (int tc = 0; tc < 8; ++tc) {
    // ---- stage x chunk: 16 batches x 64 t x 3 c -> LDS [t][c][m] ----
    {
      const int sm = tid >> 4, seg = tid & 15;
      const float* xb = x + (size_t)(b0 + sm) * (T_LEN * 3) + tc * 192 + seg * 12;
      const float4 v0 = *(const float4*)(xb + 0);
      const float4 v1 = *(const float4*)(xb + 4);
      const float4 v2 = *(const float4*)(xb + 8);
      const float vv[12] = {v0.x, v0.y, v0.z, v0.w, v1.x, v1.y, v1.z, v1.w, v2.x, v2.y, v2.z, v2.w};
#pragma unroll
      for (int jj = 0; jj < 12; ++jj) {
        const int i = seg * 12 + jj;
        *(float*)(xs + (i / 3) * 192 + (i % 3) * 64 + sm * 4) = vv[jj];
      }
    }
    __syncthreads();

#pragma unroll 2
    for (int s = 0; s < 64; ++s) {
      const int par = s & 1;
      const char* rp = hbuf + par * 2048;
      char*       wp = hbuf + (par ^ 1) * 2048;

      // x reads (barrier-independent)
      const float4 xv0 = *(const float4*)(xs + s * 192 + 0 * 64 + kg * 16);
      const float4 xv1 = *(const float4*)(xs + s * 192 + 1 * 64 + kg * 16);
      const float4 xv2 = *(const float4*)(xs + s * 192 + 2 * 64 + kg * 16);

      // A-fragments: 2 x ds_read_b128
      const short8 A0 = afrag(rp, arow, (16 * kg +  0) ^ axr);
      const short8 A1 = afrag(rp, arow, (16 * kg + 64) ^ axr);

      // MFMA: three independent 2-deep chains (one per gate)
      floatx4 aR = __builtin_amdgcn_mfma_f32_16x16x32_bf16(A0, Bh[0][0], z4, 0, 0, 0);
      aR = __builtin_amdgcn_mfma_f32_16x16x32_bf16(A1, Bh[0][1], aR, 0, 0, 0);
      floatx4 aZ = __builtin_amdgcn_mfma_f32_16x16x32_bf16(A0, Bh[1][0], z4, 0, 0, 0);
      aZ = __builtin_amdgcn_mfma_f32_16x16x32_bf16(A1, Bh[1][1], aZ, 0, 0, 0);
      floatx4 aN = __builtin_amdgcn_mfma_f32_16x16x32_bf16(A0, Bh[2][0], z4, 0, 0, 0);
      aN = __builtin_amdgcn_mfma_f32_16x16x32_bf16(A1, Bh[2][1], aN, 0, 0, 0);

      const float xa[4]  = {xv0.x, xv0.y, xv0.z, xv0.w};
      const float xb_[4] = {xv1.x, xv1.y, xv1.z, xv1.w};
      const float xc[4]  = {xv2.x, xv2.y, xv2.z, xv2.w};
#pragma unroll
      for (int r = 0; r < 4; ++r) {
        const float x0 = xa[r], x1 = xb_[r], x2 = xc[r];
        const float gr = fmaf(x0, u_r[0], fmaf(x1, u_r[1], fmaf(x2, u_r[2], c_r)));
        const float gz = fmaf(x0, u_z[0], fmaf(x1, u_z[1], fmaf(x2, u_z[2], c_z)));
        const float gn = fmaf(x0, u_n[0], fmaf(x1, u_n[1], fmaf(x2, u_n[2], c_ni)));
        const float rr = sigm(aR[r] + gr);
        const float zz = sigm(aZ[r] + gz);
        const float nv = gn + rr * (aN[r] + c_nh);
        const float nn = tanh_f(nv);
        const float hn = nn + zz * (h[r] - nn);
        h[r] = hn;
        __hip_bfloat16 bh = __float2bfloat16(hn);
        const int mrow = 4 * kg + r;
        *(unsigned short*)(wp + mrow * 128 + ((2 * u) ^ ((mrow & 7) << 4))) =
            *(const unsigned short*)&bh;
      }
      __syncthreads();
    }
  }

  // ---- FC epilogue ----
  float p[4];
#pragma unroll
  for (int r = 0; r < 4; ++r) p[r] = h[r] * wfc;
#pragma unroll
  for (int mask = 1; mask < 16; mask <<= 1) {
#pragma unroll
    for (int r = 0; r < 4; ++r) p[r] += __shfl_xor(p[r], mask);
  }
  if (ucol == 0) {
    *(float4*)(lds + (w * 16 + 4 * kg) * 4) = make_float4(p[0], p[1], p[2], p[3]);
  }
  __syncthreads();
  if (tid < 16) {
    float ssum = 0.f;
#pragma unroll
    for (int ww = 0; ww < 4; ++ww) ssum += *(const float*)(lds + (ww * 16 + tid) * 4);
    out[b0 + tid] = ssum + b_fc[0];
  }
}

extern "C" void kernel_launch(void* const* d_in, const int* in_sizes, int n_in,
                              void* d_out, int out_size, void* d_ws, size_t ws_size,
                              hipStream_t stream) {
  const float* x    = (const float*)d_in[0];
  const float* W_ih = (const float*)d_in[1];
  const float* W_hh = (const float*)d_in[2];
  const float* b_ih = (const float*)d_in[3];
  const float* b_hh = (const float*)d_in[4];
  const float* W_fc = (const float*)d_in[5];
  const float* b_fc = (const float*)d_in[6];
  float* out = (float*)d_out;

  dim3 grid(NBATCH / 16);   // 256 blocks x 16 batches; 4 waves = 4 unit-tiles
  dim3 block(256);
  gru_mfma_kernel<<<grid, block, 0, stream>>>(x, W_ih, W_hh, b_ih, b_hh, W_fc, b_fc, out);
}

// Round 16
// 216.857 us; speedup vs baseline: 2.1865x; 1.0240x over previous
//
#include <hip/hip_runtime.h>
#include <hip/hip_bf16.h>

#define T_LEN 512
#define HID 50
#define NBATCH 4096

using short8  = __attribute__((ext_vector_type(8))) short;
using floatx4 = __attribute__((ext_vector_type(4))) float;

__device__ __forceinline__ float sigm(float v) {
  return __builtin_amdgcn_rcpf(1.0f + __builtin_amdgcn_exp2f(-1.442695041f * v));
}
__device__ __forceinline__ float tanh_f(float v) {
  return 1.0f - 2.0f * __builtin_amdgcn_rcpf(1.0f + __builtin_amdgcn_exp2f(2.885390082f * v));
}

// h plane: 16 rows (m=batch) x 64 bf16 (u), row = 128 B, XOR swizzle ((m&7)<<4).
// k-bijection (W build and h reads): k = 32*f + 8*kg + e.
// SWAPPED operands: mfma(A=W, B=h) -> C[m=unit 4kg+r][n=batch ucol].
// Store: 4 consecutive unit-bf16 for one batch = ONE ds_write_b64.
__global__ __launch_bounds__(256, 1)
void gru_mfma_kernel(const float* __restrict__ x,
                     const float* __restrict__ W_ih,
                     const float* __restrict__ W_hh,
                     const float* __restrict__ b_ih,
                     const float* __restrict__ b_hh,
                     const float* __restrict__ W_fc,
                     const float* __restrict__ b_fc,
                     float* __restrict__ out) {
  // LDS: [0,12288) x-chunk [t64][c3][m16] f32 ; [12288,14336) h buf0 ; [14336,16384) h buf1
  __shared__ alignas(16) unsigned char lds[16384];
  char* xs   = (char*)lds;
  char* hbuf = (char*)lds + 12288;

  const int tid  = threadIdx.x;
  const int lane = tid & 63;
  const int w    = tid >> 6;          // wave id: owns units 16w..16w+15
  const int ucol = lane & 15;         // A-row (W build) / B-col (batch) / C-col (batch)
  const int kg   = (lane >> 4) & 3;
  const int b0   = blockIdx.x * 16;
  const int u    = 16 * w + ucol;     // W-fragment row unit
  const bool uv  = (u < HID);

  // ---- per-lane constants for the FOUR C-row units uu[r] = 16w + 4kg + r ----
  float c_r[4], c_z[4], c_ni[4], c_nh[4], wfc[4];
  float ur[4][3], uz[4][3], un[4][3];
#pragma unroll
  for (int r = 0; r < 4; ++r) {
    const int uu = 16 * w + 4 * kg + r;
    const bool vr = (uu < HID);
    c_r[r]  = vr ? (b_ih[uu] + b_hh[uu]) : 0.f;
    c_z[r]  = vr ? (b_ih[50 + uu] + b_hh[50 + uu]) : 0.f;
    c_ni[r] = vr ? b_ih[100 + uu] : 0.f;
    c_nh[r] = vr ? b_hh[100 + uu] : 0.f;
    wfc[r]  = vr ? W_fc[uu] : 0.f;
#pragma unroll
    for (int c = 0; c < 3; ++c) {
      ur[r][c] = vr ? W_ih[uu * 3 + c] : 0.f;
      uz[r][c] = vr ? W_ih[(50 + uu) * 3 + c] : 0.f;
      un[r][c] = vr ? W_ih[(100 + uu) * 3 + c] : 0.f;
    }
  }

  // ---- persistent W fragments (A operand), bf16, all three gates ----
  short8 Wf[3][2];          // gates 0=r, 1=z, 2=n ; A-row = unit u = 16w+ucol
#pragma unroll
  for (int g = 0; g < 3; ++g) {
    const int row = uv ? (g * 50 + u) : 0;
    const float* Wrow = W_hh + row * HID;
#pragma unroll
    for (int f = 0; f < 2; ++f) {
      union { short a[8]; short8 s; } ph;
#pragma unroll
      for (int e = 0; e < 8; ++e) {
        const int k = 32 * f + 8 * kg + e;
        const float v = (uv && k < HID) ? Wrow[k] : 0.f;
        __hip_bfloat16 bh = __float2bfloat16(v);
        ph.a[e] = *(short*)&bh;
      }
      Wf[g][f] = ph.s;
    }
  }

  // zero both h planes (2 x 2048 B = 4096 B)
  ((float4*)hbuf)[tid] = make_float4(0.f, 0.f, 0.f, 0.f);

  float h[4] = {0.f, 0.f, 0.f, 0.f};            // units 16w+4kg+r, batch ucol

  const int hrow = ucol * 128;                  // batch row (read & write)
  const int axr  = (ucol & 7) << 4;
  const int soff = hrow + ((32 * w + 8 * kg) ^ axr);   // b64 store offset
  const floatx4 z4 = {0.f, 0.f, 0.f, 0.f};

  for (int tc = 0; tc < 8; ++tc) {
    // ---- stage x chunk: 16 batches x 64 t x 3 c -> LDS [t][c][m] ----
    {
      const int sm = tid >> 4, seg = tid & 15;
      const float* xb = x + (size_t)(b0 + sm) * (T_LEN * 3) + tc * 192 + seg * 12;
      const float4 v0 = *(const float4*)(xb + 0);
      const float4 v1 = *(const float4*)(xb + 4);
      const float4 v2 = *(const float4*)(xb + 8);
      const float vv[12] = {v0.x, v0.y, v0.z, v0.w, v1.x, v1.y, v1.z, v1.w, v2.x, v2.y, v2.z, v2.w};
#pragma unroll
      for (int jj = 0; jj < 12; ++jj) {
        const int i = seg * 12 + jj;
        *(float*)(xs + (i / 3) * 192 + (i % 3) * 64 + sm * 4) = vv[jj];
      }
    }
    __syncthreads();

#pragma unroll 2
    for (int s = 0; s < 64; ++s) {
      const int par = s & 1;
      const char* rp = hbuf + par * 2048;
      char*       wp = hbuf + (par ^ 1) * 2048;

      // x reads: scalar (batch = ucol), kg-broadcast (conflict-free)
      const float x0 = *(const float*)(xs + s * 192 +   0 + ucol * 4);
      const float x1 = *(const float*)(xs + s * 192 +  64 + ucol * 4);
      const float x2 = *(const float*)(xs + s * 192 + 128 + ucol * 4);

      // h fragments (B operand): 2 x ds_read_b128, row = batch = ucol
      const short8 H0 = *(const short8*)(rp + hrow + ((16 * kg)      ^ axr));
      const short8 H1 = *(const short8*)(rp + hrow + ((16 * kg + 64) ^ axr));

      // MFMA (A=W, B=h): three independent 2-deep chains
      floatx4 aR = __builtin_amdgcn_mfma_f32_16x16x32_bf16(Wf[0][0], H0, z4, 0, 0, 0);
      aR = __builtin_amdgcn_mfma_f32_16x16x32_bf16(Wf[0][1], H1, aR, 0, 0, 0);
      floatx4 aZ = __builtin_amdgcn_mfma_f32_16x16x32_bf16(Wf[1][0], H0, z4, 0, 0, 0);
      aZ = __builtin_amdgcn_mfma_f32_16x16x32_bf16(Wf[1][1], H1, aZ, 0, 0, 0);
      floatx4 aN = __builtin_amdgcn_mfma_f32_16x16x32_bf16(Wf[2][0], H0, z4, 0, 0, 0);
      aN = __builtin_amdgcn_mfma_f32_16x16x32_bf16(Wf[2][1], H1, aN, 0, 0, 0);

      unsigned int hw[2];
#pragma unroll
      for (int q = 0; q < 2; ++q) {
        unsigned int pk = 0;
#pragma unroll
        for (int j = 0; j < 2; ++j) {
          const int r = 2 * q + j;
          const float gr = fmaf(x0, ur[r][0], fmaf(x1, ur[r][1], fmaf(x2, ur[r][2], c_r[r])));
          const float gz = fmaf(x0, uz[r][0], fmaf(x1, uz[r][1], fmaf(x2, uz[r][2], c_z[r])));
          const float gn = fmaf(x0, un[r][0], fmaf(x1, un[r][1], fmaf(x2, un[r][2], c_ni[r])));
          const float rr = sigm(aR[r] + gr);
          const float zz = sigm(aZ[r] + gz);
          const float omz = 1.0f - zz;
          const float zh  = zz * h[r];
          const float nn  = tanh_f(gn + rr * (aN[r] + c_nh[r]));
          h[r] = fmaf(nn, omz, zh);
          __hip_bfloat16 bh = __float2bfloat16(h[r]);
          pk |= (unsigned int)(*(const unsigned short*)&bh) << (16 * j);
        }
        hw[q] = pk;
      }
      // ONE b64 store: units 16w+4kg..+3 (consecutive bf16), batch row ucol
      *(unsigned long long*)(wp + soff) =
          (unsigned long long)hw[0] | ((unsigned long long)hw[1] << 32);
      __syncthreads();
    }
  }

  // ---- FC epilogue: out[b] = sum_u h_u * W_fc[u] + b_fc ----
  float p = h[0] * wfc[0] + h[1] * wfc[1] + h[2] * wfc[2] + h[3] * wfc[3];
  p += __shfl_xor(p, 16);
  p += __shfl_xor(p, 32);        // now every lane has its wave's 16-unit sum for batch ucol
  if (lane < 16) {
    *(float*)(lds + (w * 16 + ucol) * 4) = p;
  }
  __syncthreads();
  if (tid < 16) {
    float ssum = 0.f;
#pragma unroll
    for (int ww = 0; ww < 4; ++ww) ssum += *(const float*)(lds + (ww * 16 + tid) * 4);
    out[b0 + tid] = ssum + b_fc[0];
  }
}

extern "C" void kernel_launch(void* const* d_in, const int* in_sizes, int n_in,
                              void* d_out, int out_size, void* d_ws, size_t ws_size,
                              hipStream_t stream) {
  const float* x    = (const float*)d_in[0];
  const float* W_ih = (const float*)d_in[1];
  const float* W_hh = (const float*)d_in[2];
  const float* b_ih = (const float*)d_in[3];
  const float* b_hh = (const float*)d_in[4];
  const float* W_fc = (const float*)d_in[5];
  const float* b_fc = (const float*)d_in[6];
  float* out = (float*)d_out;

  dim3 grid(NBATCH / 16);   // 256 blocks x 16 batches; 4 waves = 4 unit-tiles
  dim3 block(256);
  gru_mfma_kernel<<<grid, block, 0, stream>>>(x, W_ih, W_hh, b_ih, b_hh, W_fc, b_fc, out);
}